// Round 9
// baseline (2078.591 us; speedup 1.0000x reference)
//
#include <hip/hip_runtime.h>

#define T_LEN 512
#define NB    32
#define HID4  1024
#define DSTR  ((size_t)T_LEN * NB * HID4)   // per-direction xg stride (elements)

typedef short  bf16x8 __attribute__((ext_vector_type(8)));
typedef float  f32x4  __attribute__((ext_vector_type(4)));

static __device__ __forceinline__ unsigned short f2bf(float f) {
  union { float f; unsigned int i; } v; v.f = f;
  unsigned int r = v.i + 0x7FFFu + ((v.i >> 16) & 1u);
  return (unsigned short)(r >> 16);
}
static __device__ __forceinline__ unsigned short f2h(float f) {
  union { _Float16 h; unsigned short u; } v; v.h = (_Float16)f; return v.u;
}
static __device__ __forceinline__ float h2f(unsigned short u) {
  union { unsigned short u; _Float16 h; } v; v.u = u; return (float)v.h;
}
static __device__ __forceinline__ float sigm(float x) {
  return __builtin_amdgcn_rcpf(1.0f + __builtin_amdgcn_exp2f(-1.44269504f * x));
}
static __device__ __forceinline__ float tanh_fast(float x) {
  float e = __builtin_amdgcn_exp2f(2.885390082f * x);
  return 1.0f - 2.0f * __builtin_amdgcn_rcpf(e + 1.0f);
}
// convert 8 consecutive f32 -> bf16x8
static __device__ __forceinline__ bf16x8 cvt8(const float* p) {
  bf16x8 r;
  #pragma unroll
  for (int i = 0; i < 8; ++i) r[i] = (short)f2bf(p[i]);
  return r;
}

// ---------------------------------------------------------------------------
// GEMM: xg = A @ W^T + bias, written in the rec-thread-swizzled layout:
//   xg[dir][t][bg(8)][tid(512)][c(8)]  (f16), c = nh*4 + gt
// (R2/R5-exact.)
// ---------------------------------------------------------------------------
__global__ __launch_bounds__(256) void gemm_xg(
    const float* __restrict__ A,
    const float* __restrict__ Wf,
    const float* __restrict__ Wb,
    const float* __restrict__ biasf,
    const float* __restrict__ biasb,
    unsigned short* __restrict__ out, int K)
{
  __shared__ __align__(16) unsigned short As[64][40];
  __shared__ __align__(16) unsigned short Bs[64][40];

  const int dir = blockIdx.z;
  const float* W    = dir ? Wb    : Wf;
  const float* bias = dir ? biasb : biasf;
  unsigned short* outd = out + (size_t)dir * DSTR;

  const int m0 = blockIdx.x * 64;
  const int n0 = blockIdx.y * 64;
  const int tid = threadIdx.x;
  const int wv = tid >> 6, lane = tid & 63;
  const int lm = lane & 15, lq = lane >> 4;
  const int mt0 = (wv >> 1) * 32, nt0 = (wv & 1) * 32;
  const int lr = tid >> 2, ls = tid & 3;

  f32x4 acc[2][2];
  #pragma unroll
  for (int a = 0; a < 2; ++a)
    #pragma unroll
    for (int b = 0; b < 2; ++b) acc[a][b] = (f32x4){0.f, 0.f, 0.f, 0.f};

  for (int kc = 0; kc < K; kc += 32) {
    *(bf16x8*)&As[lr][ls * 8] = cvt8(A + (size_t)(m0 + lr) * K + kc + ls * 8);
    *(bf16x8*)&Bs[lr][ls * 8] = cvt8(W + (size_t)(n0 + lr) * K + kc + ls * 8);
    __syncthreads();
    bf16x8 af[2], bfr[2];
    af[0]  = *(const bf16x8*)&As[mt0 + lm][lq * 8];
    af[1]  = *(const bf16x8*)&As[mt0 + 16 + lm][lq * 8];
    bfr[0] = *(const bf16x8*)&Bs[nt0 + lm][lq * 8];
    bfr[1] = *(const bf16x8*)&Bs[nt0 + 16 + lm][lq * 8];
    #pragma unroll
    for (int mt = 0; mt < 2; ++mt)
      #pragma unroll
      for (int nt = 0; nt < 2; ++nt)
        acc[mt][nt] = __builtin_amdgcn_mfma_f32_16x16x32_bf16(af[mt], bfr[nt], acc[mt][nt], 0, 0, 0);
    __syncthreads();
  }

  #pragma unroll
  for (int nt = 0; nt < 2; ++nt) {
    const int n = n0 + nt0 + nt * 16 + lm;       // gate index 0..1023
    const float bv = bias[n];
    const int gt = n >> 8, j = n & 255;
    const int wvr = j >> 5, nh = (j >> 4) & 1, lmr = j & 15;
    const int c = nh * 4 + gt;
    #pragma unroll
    for (int mt = 0; mt < 2; ++mt)
      #pragma unroll
      for (int r4 = 0; r4 < 4; ++r4) {
        const int m = m0 + mt0 + mt * 16 + lq * 4 + r4;   // token = b*T + t
        const int b = m >> 9, t = m & 511;
        const int bg = b >> 2, lqr = b & 3;
        const int tidr = wvr * 64 + lqr * 16 + lmr;
        outd[((((size_t)t * 8 + bg) * 512 + tidr) << 3) + c] = f2h(acc[mt][nt][r4] + bv);
      }
  }
}

// ---------------------------------------------------------------------------
// Recurrence. Grid = 16 blocks (dir*8 + bg), 512 threads (8 waves).
// R5 structure (777us/dispatch, best measured) + ONE change: COMPACT h buffer.
//
// Old hbuf slots were [q(4)][m(16)][e(8)] with 12 of 16 M-rows structural
// zeros (75% of A-frag LDS bytes). Gate math consumes only acc[gt][0]
// (row 4*lq); MFMA output rows 1..3 mod 4 are DISCARDED. So padding lanes
// don't need zeros -- they read DUPLICATE real data via 4-lane same-address
// broadcast (free), producing garbage only in discarded output rows.
// Compact slot [kt(8)][q(4)][m4(4)][e(8)] = 128 shorts:
//   read  addr = kt*128 + lq*32 + ((lm>>2)<<3)   (16 lines x 16B = 256
//         consecutive bytes per wave: 2-way bank alias = free, 4-lane bcast)
//   write addr = wave*128 + (lm>>3)*32 + lq*8 + (lm&7), +nh*64
// A-side LDS bank-cycles drop ~4x (~960 -> ~300 cy/CU/step): LDS total
// ~1850 cy < MFMA floor 2480 cy -> LDS stops co-limiting.
// R3's compact attempt failed from its SHARED ZERO SLOT (fixed address
// aliasing the data stripe) + per-lane selects; both are gone here.
//
// Register ledger (hard wall at 256, R7/R8 lesson): breg 192 + ar[6] 24 +
// acc 16 + xq_n 8 + addr ~12 = ~252. NO ar[8].
// vmcnt FIFO rule (R6/R7): xq must use the cross-step prefetch -- any VMEM
// value consumed in-step would wait behind the previous step's obase store
// acks. Raw s_barrier + lgkmcnt(0) only; global stores stay in flight.
// ---------------------------------------------------------------------------
__global__ __launch_bounds__(512) __attribute__((amdgpu_waves_per_eu(2, 2)))
void lstm_rec(
    const unsigned short* __restrict__ xg,   // [2][T][8][512][8] f16 (swizzled)
    const float* __restrict__ whh_f,         // [1024][256] f32
    const float* __restrict__ whh_b,
    float* __restrict__ out)                 // [32][T][512] f32, col off dir*256
{
  __shared__ __align__(16) unsigned short ldsB[65536];  // 128 frags * 1 KB
  __shared__ __align__(16) unsigned short hbuf[2048];   // 2 x [8][4][4][8] compact

  const int dir = blockIdx.x >> 3, bg = blockIdx.x & 7;
  const int b0 = bg * 4;
  const float* whh = dir ? whh_b : whh_f;
  const unsigned short* xgd = xg + (size_t)dir * DSTR;
  const int wave = threadIdx.x >> 6, lane = threadIdx.x & 63;
  const int lm = lane & 15, lq = lane >> 4;
  const int j0 = wave * 32;

  // ---- preload W_hh fragments (B-operand: n = lane&15, k = lq*8 + j) ----
  bf16x8 breg[4][2][6];
  #pragma unroll
  for (int gt = 0; gt < 4; ++gt)
    #pragma unroll
    for (int nh = 0; nh < 2; ++nh) {
      const float* wrow = whh + (size_t)(gt * 256 + j0 + nh * 16 + lm) * 256;
      #pragma unroll
      for (int kt = 0; kt < 6; ++kt)
        breg[gt][nh][kt] = cvt8(wrow + kt * 32 + lq * 8);
      #pragma unroll
      for (int kt = 6; kt < 8; ++kt) {
        const int tl = wave * 16 + gt * 4 + nh * 2 + (kt - 6);
        *(bf16x8*)(ldsB + ((size_t)tl * 64 + lane) * 8) = cvt8(wrow + kt * 32 + lq * 8);
      }
    }

  for (int i = threadIdx.x; i < 2048; i += 512) hbuf[i] = 0;
  float creg[2] = {0.f, 0.f};

  // output base: this thread's batch row is b0+lq, hidden col j0+lm (+nh*16)
  float* obase = out + (size_t)(b0 + lq) * T_LEN * 512 + dir * 256 + j0 + lm;

  // compact h write slot: value (m4=lq, col j = j0 + nh*16 + lm) ->
  //   kt=wave, q = nh*2+(lm>>3), m4 = lq, e = lm&7
  const int wb0 = wave * 128 + (lm >> 3) * 32 + lq * 8 + (lm & 7);
  // compact A read base: lane supplies row lm, k-slice q=lq; padding rows
  // (lm&3 != 0) broadcast-read their quad's real row (m4 = lm>>2)
  const int ab0 = lq * 32 + ((lm >> 2) << 3);

  // prefetch xq for step 0 (one 16B load per thread per step)
  const int tt0 = dir ? (T_LEN - 1) : 0;
  bf16x8 xq_n = *(const bf16x8*)(xgd + ((((size_t)tt0 * 8 + bg) * 512 + threadIdx.x) << 3));

  __syncthreads();

  for (int s = 0; s < T_LEN; ++s) {
    const int tt = dir ? (T_LEN - 1 - s) : s;
    const unsigned short* hr = hbuf + (s & 1) * 1024;
    unsigned short* hw = hbuf + ((s + 1) & 1) * 1024;

    const bf16x8 xq = xq_n;   // consumed this step (issued before prev stores)

    // issue prefetch for step s+1 (wraps at end: harmless in-bounds load)
    const int s1 = (s + 1) & (T_LEN - 1);
    const int tt1 = dir ? (T_LEN - 1 - s1) : s1;
    xq_n = *(const bf16x8*)(xgd + ((((size_t)tt1 * 8 + bg) * 512 + threadIdx.x) << 3));

    // A-frags for the reg-resident kts, held across both nh passes (24 VGPR)
    bf16x8 ar[6];
    #pragma unroll
    for (int kt = 0; kt < 6; ++kt)
      ar[kt] = *(const bf16x8*)(hr + kt * 128 + ab0);

    const size_t tto = (size_t)tt * 512;
    #pragma unroll
    for (int nh = 0; nh < 2; ++nh) {
      f32x4 acc[4];
      #pragma unroll
      for (int gt = 0; gt < 4; ++gt) acc[gt] = (f32x4){0.f, 0.f, 0.f, 0.f};

      __builtin_amdgcn_s_setprio(1);
      // LDS-resident kts first: B-frag reads issue early, latency hides
      #pragma unroll
      for (int kt = 6; kt < 8; ++kt) {
        const bf16x8 afrag = *(const bf16x8*)(hr + kt * 128 + ab0);
        #pragma unroll
        for (int gt = 0; gt < 4; ++gt) {
          const bf16x8 bfr = *(const bf16x8*)(ldsB + ((size_t)(wave * 16 + gt * 4 + nh * 2 + (kt - 6)) * 64 + lane) * 8);
          acc[gt] = __builtin_amdgcn_mfma_f32_16x16x32_bf16(afrag, bfr, acc[gt], 0, 0, 0);
        }
      }
      // reg-resident kts, gt-outer: acc[gt] completes after its own chain,
      // letting gate math start while later gates' MFMAs still run
      #pragma unroll
      for (int gt = 0; gt < 4; ++gt)
        #pragma unroll
        for (int kt = 0; kt < 6; ++kt)
          acc[gt] = __builtin_amdgcn_mfma_f32_16x16x32_bf16(ar[kt], breg[gt][nh][kt], acc[gt], 0, 0, 0);
      __builtin_amdgcn_s_setprio(0);

      const float iv = sigm(acc[0][0] + h2f((unsigned short)xq[nh * 4 + 0]));
      const float fv = sigm(acc[1][0] + h2f((unsigned short)xq[nh * 4 + 1]));
      const float gv = tanh_fast(acc[2][0] + h2f((unsigned short)xq[nh * 4 + 2]));
      const float ov = sigm(acc[3][0] + h2f((unsigned short)xq[nh * 4 + 3]));
      const float cv = fv * creg[nh] + iv * gv;
      creg[nh] = cv;
      const float hv = ov * tanh_fast(cv);
      hw[wb0 + nh * 64] = f2bf(hv);
      obase[tto + nh * 16] = hv;
    }

    // LDS-only fence + raw barrier: global stores/loads stay in flight.
    asm volatile("s_waitcnt lgkmcnt(0)" ::: "memory");
    __builtin_amdgcn_s_barrier();
  }
}

// ---------------------------------------------------------------------------
extern "C" void kernel_launch(void* const* d_in, const int* in_sizes, int n_in,
                              void* d_out, int out_size, void* d_ws, size_t ws_size,
                              hipStream_t stream) {
  const float* x     = (const float*)d_in[0];
  const float* wih0f = (const float*)d_in[1];
  const float* whh0f = (const float*)d_in[2];
  const float* b0f   = (const float*)d_in[3];
  const float* wih0b = (const float*)d_in[4];
  const float* whh0b = (const float*)d_in[5];
  const float* b0b   = (const float*)d_in[6];
  const float* wih1f = (const float*)d_in[7];
  const float* whh1f = (const float*)d_in[8];
  const float* b1f   = (const float*)d_in[9];
  const float* wih1b = (const float*)d_in[10];
  const float* whh1b = (const float*)d_in[11];
  const float* b1b   = (const float*)d_in[12];
  float* out = (float*)d_out;

  // ws: xg only — [2][T][8][512][8] f16 = 64 MiB. Layer-0 hidden states are
  // routed through d_out (f32, fully overwritten by the layer-1 recurrence).
  unsigned short* xg = (unsigned short*)d_ws;

  gemm_xg<<<dim3(256, 16, 2), 256, 0, stream>>>(x,   wih0f, wih0b, b0f, b0b, xg, 256);
  lstm_rec<<<16, 512, 0, stream>>>(xg, whh0f, whh0b, out);   // h1 -> d_out (f32)
  gemm_xg<<<dim3(256, 16, 2), 256, 0, stream>>>(out, wih1f, wih1b, b1f, b1b, xg, 512);
  lstm_rec<<<16, 512, 0, stream>>>(xg, whh1f, whh1b, out);
}

// Round 10
// 1828.837 us; speedup vs baseline: 1.1366x; 1.1366x over previous
//
#include <hip/hip_runtime.h>

#define T_LEN 512
#define NB    32
#define HID4  1024
#define DSTR  ((size_t)T_LEN * NB * HID4)   // per-direction xg stride (elements)

typedef short  bf16x8 __attribute__((ext_vector_type(8)));
typedef float  f32x4  __attribute__((ext_vector_type(4)));

static __device__ __forceinline__ unsigned short f2bf(float f) {
  union { float f; unsigned int i; } v; v.f = f;
  unsigned int r = v.i + 0x7FFFu + ((v.i >> 16) & 1u);
  return (unsigned short)(r >> 16);
}
static __device__ __forceinline__ unsigned short f2h(float f) {
  union { _Float16 h; unsigned short u; } v; v.h = (_Float16)f; return v.u;
}
static __device__ __forceinline__ float h2f(unsigned short u) {
  union { unsigned short u; _Float16 h; } v; v.u = u; return (float)v.h;
}
static __device__ __forceinline__ float sigm(float x) {
  return __builtin_amdgcn_rcpf(1.0f + __builtin_amdgcn_exp2f(-1.44269504f * x));
}
static __device__ __forceinline__ float tanh_fast(float x) {
  float e = __builtin_amdgcn_exp2f(2.885390082f * x);
  return 1.0f - 2.0f * __builtin_amdgcn_rcpf(e + 1.0f);
}
// convert 8 consecutive f32 -> bf16x8
static __device__ __forceinline__ bf16x8 cvt8(const float* p) {
  bf16x8 r;
  #pragma unroll
  for (int i = 0; i < 8; ++i) r[i] = (short)f2bf(p[i]);
  return r;
}

// ---------------------------------------------------------------------------
// GEMM: xg = A @ W^T + bias, written in the rec-thread-swizzled layout:
//   xg[dir][t][bg(8)][tid(512)][c(8)]  (f16), c = nh*4 + gt
// 64x128 tile (was 64x64): halves per-output A staging + f32->bf16 convert
// VALU (the measured bottleneck: ~114 TF, nowhere near MFMA-bound).
// Grid (256, 8, 2); 4 waves; K-chunks of 32. Epilogue mapping is a pure
// function of n -- unchanged from the R5 kernel.
// ---------------------------------------------------------------------------
__global__ __launch_bounds__(256) void gemm_xg(
    const float* __restrict__ A,
    const float* __restrict__ Wf,
    const float* __restrict__ Wb,
    const float* __restrict__ biasf,
    const float* __restrict__ biasb,
    unsigned short* __restrict__ out, int K)
{
  __shared__ __align__(16) unsigned short As[64][40];
  __shared__ __align__(16) unsigned short Bs[128][40];

  const int dir = blockIdx.z;
  const float* W    = dir ? Wb    : Wf;
  const float* bias = dir ? biasb : biasf;
  unsigned short* outd = out + (size_t)dir * DSTR;

  const int m0 = blockIdx.x * 64;
  const int n0 = blockIdx.y * 128;
  const int tid = threadIdx.x;
  const int wv = tid >> 6, lane = tid & 63;
  const int lm = lane & 15, lq = lane >> 4;
  const int mt0 = (wv >> 1) * 32, nt0 = (wv & 1) * 32;
  const int lr = tid >> 2, ls = tid & 3;

  f32x4 acc[2][2][2];   // [ns][mt][nt]
  #pragma unroll
  for (int c = 0; c < 2; ++c)
    #pragma unroll
    for (int a = 0; a < 2; ++a)
      #pragma unroll
      for (int b = 0; b < 2; ++b) acc[c][a][b] = (f32x4){0.f, 0.f, 0.f, 0.f};

  for (int kc = 0; kc < K; kc += 32) {
    *(bf16x8*)&As[lr][ls * 8]      = cvt8(A + (size_t)(m0 + lr) * K + kc + ls * 8);
    *(bf16x8*)&Bs[lr][ls * 8]      = cvt8(W + (size_t)(n0 + lr) * K + kc + ls * 8);
    *(bf16x8*)&Bs[64 + lr][ls * 8] = cvt8(W + (size_t)(n0 + 64 + lr) * K + kc + ls * 8);
    __syncthreads();
    bf16x8 af[2];
    af[0] = *(const bf16x8*)&As[mt0 + lm][lq * 8];
    af[1] = *(const bf16x8*)&As[mt0 + 16 + lm][lq * 8];
    #pragma unroll
    for (int ns = 0; ns < 2; ++ns) {
      bf16x8 bfr[2];
      bfr[0] = *(const bf16x8*)&Bs[ns * 64 + nt0 + lm][lq * 8];
      bfr[1] = *(const bf16x8*)&Bs[ns * 64 + nt0 + 16 + lm][lq * 8];
      #pragma unroll
      for (int mt = 0; mt < 2; ++mt)
        #pragma unroll
        for (int nt = 0; nt < 2; ++nt)
          acc[ns][mt][nt] = __builtin_amdgcn_mfma_f32_16x16x32_bf16(af[mt], bfr[nt], acc[ns][mt][nt], 0, 0, 0);
    }
    __syncthreads();
  }

  #pragma unroll
  for (int ns = 0; ns < 2; ++ns)
    #pragma unroll
    for (int nt = 0; nt < 2; ++nt) {
      const int n = n0 + ns * 64 + nt0 + nt * 16 + lm;   // gate index 0..1023
      const float bv = bias[n];
      const int gt = n >> 8, j = n & 255;
      const int wvr = j >> 5, nh = (j >> 4) & 1, lmr = j & 15;
      const int c = nh * 4 + gt;
      #pragma unroll
      for (int mt = 0; mt < 2; ++mt)
        #pragma unroll
        for (int r4 = 0; r4 < 4; ++r4) {
          const int m = m0 + mt0 + mt * 16 + lq * 4 + r4;   // token = b*T + t
          const int b = m >> 9, t = m & 511;
          const int bg = b >> 2, lqr = b & 3;
          const int tidr = wvr * 64 + lqr * 16 + lmr;
          outd[((((size_t)t * 8 + bg) * 512 + tidr) << 3) + c] = f2h(acc[ns][mt][nt][r4] + bv);
        }
    }
}

// ---------------------------------------------------------------------------
// Recurrence: R5 EXACT (777us/dispatch, best measured across 9 rounds).
// Grid = 16 blocks (dir*8 + bg), 512 threads (8 waves).
// - breg[4][2][6]: kt0..5 weights register-resident (192 VGPR); kt6,7 in LDS.
// - Per nh-pass: LDS-kts (6,7) FIRST (B-reads issue right after barrier),
//   then reg-kts gt-outer with ar[6] (acc[gt] finishes after its own chain:
//   gate math overlaps later gates' MFMAs). setprio(1) around MFMA cluster.
// - xq: cross-step prefetch ONLY (vmcnt FIFO rule, R6/R7: in-step VMEM
//   consumption waits behind prior obase store-acks).
// - Raw s_barrier + lgkmcnt(0) only; global stores stay in flight.
// Closed levers (measured dead): ar[8] (spill, R8), compact-A broadcast
// (b128 is return-bus-bound, R3/R9), L2-streamed B (R6), j-split (R4).
// ---------------------------------------------------------------------------
__global__ __launch_bounds__(512) __attribute__((amdgpu_waves_per_eu(2, 2)))
void lstm_rec(
    const unsigned short* __restrict__ xg,   // [2][T][8][512][8] f16 (swizzled)
    const float* __restrict__ whh_f,         // [1024][256] f32
    const float* __restrict__ whh_b,
    float* __restrict__ out)                 // [32][T][512] f32, col off dir*256
{
  __shared__ __align__(16) unsigned short ldsB[65536];  // 128 frags * 1 KB
  __shared__ __align__(16) unsigned short hbuf[8192];   // [2][8][4][16][8]

  const int dir = blockIdx.x >> 3, bg = blockIdx.x & 7;
  const int b0 = bg * 4;
  const float* whh = dir ? whh_b : whh_f;
  const unsigned short* xgd = xg + (size_t)dir * DSTR;
  const int wave = threadIdx.x >> 6, lane = threadIdx.x & 63;
  const int lm = lane & 15, lq = lane >> 4;
  const int j0 = wave * 32;

  // ---- preload W_hh fragments (B-operand: n = lane&15, k = lq*8 + j) ----
  bf16x8 breg[4][2][6];
  #pragma unroll
  for (int gt = 0; gt < 4; ++gt)
    #pragma unroll
    for (int nh = 0; nh < 2; ++nh) {
      const float* wrow = whh + (size_t)(gt * 256 + j0 + nh * 16 + lm) * 256;
      #pragma unroll
      for (int kt = 0; kt < 6; ++kt)
        breg[gt][nh][kt] = cvt8(wrow + kt * 32 + lq * 8);
      #pragma unroll
      for (int kt = 6; kt < 8; ++kt) {
        const int tl = wave * 16 + gt * 4 + nh * 2 + (kt - 6);
        *(bf16x8*)(ldsB + ((size_t)tl * 64 + lane) * 8) = cvt8(wrow + kt * 32 + lq * 8);
      }
    }

  for (int i = threadIdx.x; i < 8192; i += 512) hbuf[i] = 0;
  float creg[2] = {0.f, 0.f};

  // output base: this thread's batch row is b0+lq, hidden col j0+lm (+nh*16)
  float* obase = out + (size_t)(b0 + lq) * T_LEN * 512 + dir * 256 + j0 + lm;

  // h write slot (A-frag-native): value (m=4*lq, col jfull=j0+nh*16+lm) ->
  // kt'=wave, quad'=nh*2+(lm>>3), row'=4*lq, e=lm&7; nh adds 256 shorts.
  const int wb0 = wave * 512 + (lm >> 3) * 128 + lq * 32 + (lm & 7);

  // prefetch xq for step 0 (one 16B load per thread per step)
  const int tt0 = dir ? (T_LEN - 1) : 0;
  bf16x8 xq_n = *(const bf16x8*)(xgd + ((((size_t)tt0 * 8 + bg) * 512 + threadIdx.x) << 3));

  __syncthreads();

  for (int s = 0; s < T_LEN; ++s) {
    const int tt = dir ? (T_LEN - 1 - s) : s;
    const unsigned short* hr = hbuf + (s & 1) * 4096;
    unsigned short* hw = hbuf + ((s + 1) & 1) * 4096;

    const bf16x8 xq = xq_n;   // consumed this step

    // issue prefetch for step s+1: latency spans the whole step
    const int s1 = (s + 1 < T_LEN) ? (s + 1) : s;
    const int tt1 = dir ? (T_LEN - 1 - s1) : s1;
    xq_n = *(const bf16x8*)(xgd + ((((size_t)tt1 * 8 + bg) * 512 + threadIdx.x) << 3));

    // A-frags for the reg-resident kts, held across both nh passes (24 VGPR)
    bf16x8 ar[6];
    #pragma unroll
    for (int kt = 0; kt < 6; ++kt)
      ar[kt] = *(const bf16x8*)(hr + kt * 512 + lane * 8);

    const size_t tto = (size_t)tt * 512;
    #pragma unroll
    for (int nh = 0; nh < 2; ++nh) {
      f32x4 acc[4];
      #pragma unroll
      for (int gt = 0; gt < 4; ++gt) acc[gt] = (f32x4){0.f, 0.f, 0.f, 0.f};

      __builtin_amdgcn_s_setprio(1);
      // LDS-resident kts first: B-frag reads issue early, latency hides
      #pragma unroll
      for (int kt = 6; kt < 8; ++kt) {
        const bf16x8 afrag = *(const bf16x8*)(hr + kt * 512 + lane * 8);
        #pragma unroll
        for (int gt = 0; gt < 4; ++gt) {
          const bf16x8 bfr = *(const bf16x8*)(ldsB + ((size_t)(wave * 16 + gt * 4 + nh * 2 + (kt - 6)) * 64 + lane) * 8);
          acc[gt] = __builtin_amdgcn_mfma_f32_16x16x32_bf16(afrag, bfr, acc[gt], 0, 0, 0);
        }
      }
      // reg-resident kts, gt-outer: acc[gt] completes after its own chain,
      // letting gate math start while later gates' MFMAs still run
      #pragma unroll
      for (int gt = 0; gt < 4; ++gt)
        #pragma unroll
        for (int kt = 0; kt < 6; ++kt)
          acc[gt] = __builtin_amdgcn_mfma_f32_16x16x32_bf16(ar[kt], breg[gt][nh][kt], acc[gt], 0, 0, 0);
      __builtin_amdgcn_s_setprio(0);

      const float iv = sigm(acc[0][0] + h2f((unsigned short)xq[nh * 4 + 0]));
      const float fv = sigm(acc[1][0] + h2f((unsigned short)xq[nh * 4 + 1]));
      const float gv = tanh_fast(acc[2][0] + h2f((unsigned short)xq[nh * 4 + 2]));
      const float ov = sigm(acc[3][0] + h2f((unsigned short)xq[nh * 4 + 3]));
      const float cv = fv * creg[nh] + iv * gv;
      creg[nh] = cv;
      const float hv = ov * tanh_fast(cv);
      hw[wb0 + nh * 256] = f2bf(hv);
      obase[tto + nh * 16] = hv;
    }

    // LDS-only fence + raw barrier: global stores/load stay in flight.
    asm volatile("s_waitcnt lgkmcnt(0)" ::: "memory");
    __builtin_amdgcn_s_barrier();
  }
}

// ---------------------------------------------------------------------------
extern "C" void kernel_launch(void* const* d_in, const int* in_sizes, int n_in,
                              void* d_out, int out_size, void* d_ws, size_t ws_size,
                              hipStream_t stream) {
  const float* x     = (const float*)d_in[0];
  const float* wih0f = (const float*)d_in[1];
  const float* whh0f = (const float*)d_in[2];
  const float* b0f   = (const float*)d_in[3];
  const float* wih0b = (const float*)d_in[4];
  const float* whh0b = (const float*)d_in[5];
  const float* b0b   = (const float*)d_in[6];
  const float* wih1f = (const float*)d_in[7];
  const float* whh1f = (const float*)d_in[8];
  const float* b1f   = (const float*)d_in[9];
  const float* wih1b = (const float*)d_in[10];
  const float* whh1b = (const float*)d_in[11];
  const float* b1b   = (const float*)d_in[12];
  float* out = (float*)d_out;

  // ws: xg only — [2][T][8][512][8] f16 = 64 MiB. Layer-0 hidden states are
  // routed through d_out (f32, fully overwritten by the layer-1 recurrence).
  unsigned short* xg = (unsigned short*)d_ws;

  gemm_xg<<<dim3(256, 8, 2), 256, 0, stream>>>(x,   wih0f, wih0b, b0f, b0b, xg, 256);
  lstm_rec<<<16, 512, 0, stream>>>(xg, whh0f, whh0b, out);   // h1 -> d_out (f32)
  gemm_xg<<<dim3(256, 8, 2), 256, 0, stream>>>(out, wih1f, wih1b, b1f, b1b, xg, 512);
  lstm_rec<<<16, 512, 0, stream>>>(xg, whh1f, whh1b, out);
}